// Round 1
// 415.178 us; speedup vs baseline: 1.0048x; 1.0048x over previous
//
#include <hip/hip_runtime.h>
#include <hip/hip_bf16.h>

// B=65536 rows, F=256 features, T=256 trees, DEPTH=6, C=4 classes.
#define NB 65536
#define NF 256
#define NT 256
#define NC 4
#define NG 8             // tree groups (32 trees each)
#define TG 32
#define RB 128           // row-blocks
#define RPB (NB / RB)    // 512 rows per block
#define RPC 16           // rows per chunk (2 chains per thread)
#define NCHUNK (RPB / RPC)  // 32
#define NTHREADS 256

// Order-preserving float32 -> uint32 (inputs have no NaNs).
__device__ __forceinline__ unsigned int mono32(float v) {
    unsigned int u = __float_as_uint(v);
    return (u & 0x80000000u) ? ~u : (u | 0x80000000u);
}

// Block = (tree-group g, 32 trees) x (row-block rb, 512 rows).
// Levels 0..2 of each thread's tree live in REGISTERS; levels 3..5 in LDS,
// stored TRANSPOSED [entry][tree] so per-level lookups tbl[p*32+lt] hit
// bank (2*lt)%32 -> exact 2-way (free on wave64) instead of ~4-way random.
// x rows staged via global_load_lds (no ds_write issue slots).
// Argmax over the group's 32 trees: multi-class butterfly (9 shfl_xor for
// all 4 classes) + 4 broadcast shfl + ballot/ffs first-occurrence, merged
// across groups via monotone-u64 atomicMax in ws.
__global__ __launch_bounds__(NTHREADS, 4) void k_traverse(
    const float* __restrict__ x,
    const int*   __restrict__ root_nodes, const float* __restrict__ root_biases,
    const float* __restrict__ leaf_nodes,
    const int* __restrict__ n1, const float* __restrict__ b1,
    const int* __restrict__ n2, const float* __restrict__ b2,
    const int* __restrict__ n3, const float* __restrict__ b3,
    const int* __restrict__ n4, const float* __restrict__ b4,
    const int* __restrict__ n5, const float* __restrict__ b5,
    float* __restrict__ out_val,                 // [B, T, C]
    unsigned long long* __restrict__ keys)       // [B, C]
{
    const int g  = blockIdx.x >> 7;        // tree group 0..7
    const int rb = blockIdx.x & (RB - 1);  // row block 0..127

    __shared__ int2  tbl[1792];     // l3 @0 (256), l4 @256 (512), l5 @768 (1024) — transposed [p][tree]
    __shared__ float xr[RPC * NF];  // 16 staged rows (16 KB)

    const int tid = threadIdx.x;
    const int rs  = tid >> 5;       // row slot 0..7
    const int lt  = tid & 31;       // local tree
    const int t   = g * TG + lt;    // global tree

    // ---- per-thread register tables: root + levels 1,2 ----
    const int2 e0   = make_int2(root_nodes[t], __float_as_int(root_biases[t]));
    const int2 e1_0 = make_int2(n1[2 * t],     __float_as_int(b1[2 * t]));
    const int2 e1_1 = make_int2(n1[2 * t + 1], __float_as_int(b1[2 * t + 1]));
    const int2 e2_0 = make_int2(n2[4 * t],     __float_as_int(b2[4 * t]));
    const int2 e2_1 = make_int2(n2[4 * t + 1], __float_as_int(b2[4 * t + 1]));
    const int2 e2_2 = make_int2(n2[4 * t + 2], __float_as_int(b2[4 * t + 2]));
    const int2 e2_3 = make_int2(n2[4 * t + 3], __float_as_int(b2[4 * t + 3]));

    // ---- stage levels 3..5 for this group into LDS, TRANSPOSED ----
    // source is tree-major (i = tree*W + p); dest idx = p*32 + tree.
    {
        const int i = tid;                             // level 3: W=8
        tbl[((i & 7) << 5) | (i >> 3)] =
            make_int2(n3[g * 256 + i], __float_as_int(b3[g * 256 + i]));
    }
    #pragma unroll
    for (int k = 0; k < 2; ++k) {                      // level 4: W=16
        const int i = tid + 256 * k;
        tbl[256 + ((i & 15) << 5) + (i >> 4)] =
            make_int2(n4[g * 512 + i], __float_as_int(b4[g * 512 + i]));
    }
    #pragma unroll
    for (int k = 0; k < 4; ++k) {                      // level 5: W=32
        const int i = tid + 256 * k;
        tbl[768 + ((i & 31) << 5) + (i >> 5)] =
            make_int2(n5[g * 1024 + i], __float_as_int(b5[g * 1024 + i]));
    }

    const float4* xg  = (const float4*)x;
    const float4* lf4 = (const float4*)leaf_nodes;
    float4*       ov4 = (float4*)out_val;
    const int halfshift = tid & 32;   // ballot half select

    for (int ck = 0; ck < NCHUNK; ++ck) {
        const int r0 = rb * RPB + ck * RPC;

        // stage 16 rows = 1024 float4, coalesced, direct global->LDS
        // (dest = wave-uniform base + lane*16: the legal linear pattern)
        {
            const size_t base4 = (size_t)r0 * (NF / 4);
            float4* xr4 = (float4*)xr;
            #pragma unroll
            for (int k = 0; k < 4; ++k) {
                __builtin_amdgcn_global_load_lds(
                    (const __attribute__((address_space(1))) void*)(xg + base4 + tid + 256 * k),
                    (__attribute__((address_space(3))) void*)(xr4 + tid + 256 * k),
                    16, 0, 0);
            }
        }
        __syncthreads();   // drains vmcnt (global_load_lds) + covers tbl staging on ck==0

        const float* xrow0 = xr + rs * NF;
        const float* xrow1 = xr + (rs + 8) * NF;
        int p0, p1;
        int2 ea, eb;

        // root (regs)
        p0 = (xrow0[e0.x] >= __int_as_float(e0.y)) ? 1 : 0;
        p1 = (xrow1[e0.x] >= __int_as_float(e0.y)) ? 1 : 0;
        // level 1 (regs)
        ea = p0 ? e1_1 : e1_0;
        eb = p1 ? e1_1 : e1_0;
        p0 = 2 * p0 + (xrow0[ea.x] >= __int_as_float(ea.y) ? 1 : 0);
        p1 = 2 * p1 + (xrow1[eb.x] >= __int_as_float(eb.y) ? 1 : 0);
        // level 2 (regs, 4-way select)
        {
            int2 a0 = (p0 & 1) ? e2_1 : e2_0, a1 = (p0 & 1) ? e2_3 : e2_2;
            ea = (p0 & 2) ? a1 : a0;
            int2 c0 = (p1 & 1) ? e2_1 : e2_0, c1 = (p1 & 1) ? e2_3 : e2_2;
            eb = (p1 & 2) ? c1 : c0;
        }
        p0 = 2 * p0 + (xrow0[ea.x] >= __int_as_float(ea.y) ? 1 : 0);
        p1 = 2 * p1 + (xrow1[eb.x] >= __int_as_float(eb.y) ? 1 : 0);
        // level 3 (LDS, transposed: p in [0,8))
        ea = tbl[(p0 << 5) + lt];
        eb = tbl[(p1 << 5) + lt];
        p0 = 2 * p0 + (xrow0[ea.x] >= __int_as_float(ea.y) ? 1 : 0);
        p1 = 2 * p1 + (xrow1[eb.x] >= __int_as_float(eb.y) ? 1 : 0);
        // level 4 (LDS, transposed: p in [0,16))
        ea = tbl[256 + (p0 << 5) + lt];
        eb = tbl[256 + (p1 << 5) + lt];
        p0 = 2 * p0 + (xrow0[ea.x] >= __int_as_float(ea.y) ? 1 : 0);
        p1 = 2 * p1 + (xrow1[eb.x] >= __int_as_float(eb.y) ? 1 : 0);
        // level 5 (LDS, transposed: p in [0,32))
        ea = tbl[768 + (p0 << 5) + lt];
        eb = tbl[768 + (p1 << 5) + lt];
        p0 = 2 * p0 + (xrow0[ea.x] >= __int_as_float(ea.y) ? 1 : 0);
        p1 = 2 * p1 + (xrow1[eb.x] >= __int_as_float(eb.y) ? 1 : 0);

        // leaves (global, L2-hot) + coalesced out_val stores
        const float4 leaf0 = lf4[(size_t)g * 2048 + (lt << 6) + p0];
        const float4 leaf1 = lf4[(size_t)g * 2048 + (lt << 6) + p1];
        ov4[(size_t)(r0 + rs)     * NT + t] = leaf0;
        ov4[(size_t)(r0 + rs + 8) * NT + t] = leaf1;

        // ---- argmax over this group's 32 trees, per (row,class) ----
        // Multi-class butterfly: all 4 class maxima in 9 shfl_xor (vs 20),
        // ending with class (2*bit4 + bit3) of lt holding its global max.
        #pragma unroll
        for (int c2 = 0; c2 < 2; ++c2) {
            const float4 lv = c2 ? leaf1 : leaf0;
            const int row = r0 + rs + 8 * c2;
            const float vc0 = lv.x, vc1 = lv.y, vc2 = lv.z, vc3 = lv.w;

            // step 1 (mask 16): 4 shfl, keep 2 values per lane
            const float a0 = fmaxf(vc0, __shfl_xor(vc0, 16));
            const float a1 = fmaxf(vc1, __shfl_xor(vc1, 16));
            const float a2 = fmaxf(vc2, __shfl_xor(vc2, 16));
            const float a3 = fmaxf(vc3, __shfl_xor(vc3, 16));
            const bool hi4 = (lt & 16) != 0;
            float u = hi4 ? a2 : a0;   // class 2*bit4 + 0
            float w = hi4 ? a3 : a1;   // class 2*bit4 + 1
            // step 2 (mask 8): 2 shfl, keep 1 value per lane
            const float mu = fmaxf(u, __shfl_xor(u, 8));
            const float mw = fmaxf(w, __shfl_xor(w, 8));
            float v = (lt & 8) ? mw : mu;
            // steps 3-5 (masks 4,2,1): 1 shfl each
            v = fmaxf(v, __shfl_xor(v, 4));
            v = fmaxf(v, __shfl_xor(v, 2));
            v = fmaxf(v, __shfl_xor(v, 1));
            // lane lt now holds global max of class (2*(lt>>4&1) + (lt>>3&1))

            const float vcarr[4] = { vc0, vc1, vc2, vc3 };
            unsigned long long kk = 0;
            #pragma unroll
            for (int cls = 0; cls < 4; ++cls) {
                // broadcast class max from lane (cls*8) of own half
                const float mc = __shfl(v, halfshift + (cls << 3));
                const unsigned long long ball = __ballot(vcarr[cls] == mc);
                const unsigned int hm = (unsigned int)(ball >> halfshift);
                const int gidx = g * TG + (__ffs(hm) - 1);   // first occurrence
                const unsigned long long kc =
                    ((unsigned long long)mono32(mc) << 8) |
                    (unsigned long long)(255 - gidx);
                if (lt == cls) kk = kc;
            }
            if (lt < 4) atomicMax(&keys[(size_t)row * NC + lt], kk);
        }
        __syncthreads();   // protect xr before next chunk's staging
    }
}

__global__ void __launch_bounds__(256) k_finish(
    const unsigned long long* __restrict__ keys,
    float* __restrict__ out_arg)   // [B, C]
{
    const int i = blockIdx.x * 256 + threadIdx.x;
    out_arg[i] = (float)(255 - (int)(keys[i] & 0xFFull));
}

extern "C" void kernel_launch(void* const* d_in, const int* in_sizes, int n_in,
                              void* d_out, int out_size, void* d_ws, size_t ws_size,
                              hipStream_t stream) {
    const float* x           = (const float*)d_in[0];
    const int*   root_nodes  = (const int*)  d_in[1];
    const float* root_biases = (const float*)d_in[2];
    const float* leaf_nodes  = (const float*)d_in[3];
    const int*   n1 = (const int*)  d_in[4];
    const float* b1 = (const float*)d_in[5];
    const int*   n2 = (const int*)  d_in[6];
    const float* b2 = (const float*)d_in[7];
    const int*   n3 = (const int*)  d_in[8];
    const float* b3 = (const float*)d_in[9];
    const int*   n4 = (const int*)  d_in[10];
    const float* b4 = (const float*)d_in[11];
    const int*   n5 = (const int*)  d_in[12];
    const float* b5 = (const float*)d_in[13];

    float* out_arg = (float*)d_out;                    // [B, C]
    float* out_val = (float*)d_out + (size_t)NB * NC;  // [B, T, C]
    unsigned long long* keys = (unsigned long long*)d_ws;

    hipMemsetAsync(d_ws, 0, (size_t)NB * NC * sizeof(unsigned long long), stream);

    k_traverse<<<NG * RB, NTHREADS, 0, stream>>>(
        x, root_nodes, root_biases, leaf_nodes,
        n1, b1, n2, b2, n3, b3, n4, b4, n5, b5,
        out_val, keys);

    k_finish<<<(NB * NC) / 256, 256, 0, stream>>>(keys, out_arg);
}

// Round 2
// 411.981 us; speedup vs baseline: 1.0126x; 1.0078x over previous
//
#include <hip/hip_runtime.h>

// B=65536 rows, F=256 features, T=256 trees, DEPTH=6, C=4 classes.
#define NB 65536
#define NF 256
#define NT 256
#define NC 4
#define NG 8             // tree groups (32 trees each), one per wave
#define TG 32
#define RB 512           // row-blocks = grid size
#define RPB (NB / RB)    // 128 rows per block
#define RPC 8            // rows per chunk
#define NCHUNK (RPB / RPC)  // 16
#define NTHREADS 512     // 8 waves, wave w = tree group w

// Order-preserving float32 -> uint32 (inputs have no NaNs).
__device__ __forceinline__ unsigned int mono32(float v) {
    unsigned int u = __float_as_uint(v);
    return (u & 0x80000000u) ? ~u : (u | 0x80000000u);
}

// Block = row-range of 128 rows x ALL 256 trees (8 waves = 8 tree groups).
// x is therefore staged ONCE per row (was 8x across group-blocks) -> read
// stream drops 512->64 MB. Levels 0..2 per-thread in registers; levels 3,4
// for all 8 groups in LDS (48 KB, transposed [p][tree] -> 2-way banks);
// level 5 gathered from L2-hot global (64 KB tables). xr double-buffered:
// chunk k+1 prefetched via global_load_lds before chunk k's chains, drained
// by the end-of-chunk barrier -> latency hidden. Argmax: per-wave 32-tree
// multiclass butterfly, then cross-group combine in LDS (no atomics, no
// workspace, no finish kernel).
__global__ __launch_bounds__(NTHREADS, 4) void k_traverse(
    const float* __restrict__ x,
    const int*   __restrict__ root_nodes, const float* __restrict__ root_biases,
    const float* __restrict__ leaf_nodes,
    const int* __restrict__ n1, const float* __restrict__ b1,
    const int* __restrict__ n2, const float* __restrict__ b2,
    const int* __restrict__ n3, const float* __restrict__ b3,
    const int* __restrict__ n4, const float* __restrict__ b4,
    const int* __restrict__ n5, const float* __restrict__ b5,
    float* __restrict__ out_val,   // [B, T, C]
    float* __restrict__ out_arg)   // [B, C]
{
    const int rb = blockIdx.x;

    __shared__ int2  tbl[6144];           // l3 [0,2048): g*256+p*32+lt ; l4 [2048,6144): +g*512+p*32+lt
    __shared__ float xr[2][RPC * NF];     // double-buffered 8-row stage (2 x 8 KB)
    __shared__ unsigned long long wkey[RPC][NC][NG];  // per-group argmax keys (2 KB)

    const int tid  = threadIdx.x;
    const int g    = tid >> 6;        // wave = tree group 0..7
    const int lane = tid & 63;
    const int lt   = lane & 31;       // local tree
    const int h    = lane >> 5;       // half: row parity
    const int t    = g * TG + lt;     // global tree
    const int halfshift = lane & 32;  // ballot half select

    // ---- per-thread register tables: root + levels 1,2 ----
    const int2 e0   = make_int2(root_nodes[t], __float_as_int(root_biases[t]));
    const int2 e1_0 = make_int2(n1[2 * t],     __float_as_int(b1[2 * t]));
    const int2 e1_1 = make_int2(n1[2 * t + 1], __float_as_int(b1[2 * t + 1]));
    const int2 e2_0 = make_int2(n2[4 * t],     __float_as_int(b2[4 * t]));
    const int2 e2_1 = make_int2(n2[4 * t + 1], __float_as_int(b2[4 * t + 1]));
    const int2 e2_2 = make_int2(n2[4 * t + 2], __float_as_int(b2[4 * t + 2]));
    const int2 e2_3 = make_int2(n2[4 * t + 3], __float_as_int(b2[4 * t + 3]));

    // ---- stage levels 3,4 for ALL groups into LDS, transposed [p][tree] ----
    #pragma unroll
    for (int k = 0; k < 4; ++k) {                      // level 3: 2048 entries (t*8+p)
        const int i = tid + 512 * k;
        const int tt = i >> 3, p = i & 7;
        tbl[((tt >> 5) << 8) + (p << 5) + (tt & 31)] =
            make_int2(n3[i], __float_as_int(b3[i]));
    }
    #pragma unroll
    for (int k = 0; k < 8; ++k) {                      // level 4: 4096 entries (t*16+p)
        const int i = tid + 512 * k;
        const int tt = i >> 4, p = i & 15;
        tbl[2048 + ((tt >> 5) << 9) + (p << 5) + (tt & 31)] =
            make_int2(n4[i], __float_as_int(b4[i]));
    }

    const float4* xg  = (const float4*)x;
    const float4* lf4 = (const float4*)leaf_nodes;
    float4*       ov4 = (float4*)out_val;

    // ---- prologue: stage chunk 0 into buffer 0 ----
    {
        const size_t base4 = (size_t)rb * RPB * (NF / 4);
        __builtin_amdgcn_global_load_lds(
            (const __attribute__((address_space(1))) void*)(xg + base4 + tid),
            (__attribute__((address_space(3))) void*)(((float4*)xr[0]) + tid),
            16, 0, 0);
    }
    __syncthreads();   // tables + chunk-0 stage complete

    int buf = 0;
    for (int ck = 0; ck < NCHUNK; ++ck) {
        const int r0 = rb * RPB + ck * RPC;

        // prefetch chunk ck+1 into the other buffer (drained by barrier below)
        if (ck + 1 < NCHUNK) {
            const size_t base4 = (size_t)(r0 + RPC) * (NF / 4);
            __builtin_amdgcn_global_load_lds(
                (const __attribute__((address_space(1))) void*)(xg + base4 + tid),
                (__attribute__((address_space(3))) void*)(((float4*)xr[buf ^ 1]) + tid),
                16, 0, 0);
        }

        // ---- 4 independent chains: rows h, h+2, h+4, h+6 ----
        const float* xb = xr[buf];
        const float* xw[4];
        int p[4];
        #pragma unroll
        for (int j = 0; j < 4; ++j) xw[j] = xb + (h + 2 * j) * NF;

        // root (regs)
        #pragma unroll
        for (int j = 0; j < 4; ++j)
            p[j] = (xw[j][e0.x] >= __int_as_float(e0.y)) ? 1 : 0;
        // level 1 (regs)
        #pragma unroll
        for (int j = 0; j < 4; ++j) {
            const int2 e = p[j] ? e1_1 : e1_0;
            p[j] = 2 * p[j] + (xw[j][e.x] >= __int_as_float(e.y) ? 1 : 0);
        }
        // level 2 (regs, 4-way select)
        #pragma unroll
        for (int j = 0; j < 4; ++j) {
            const int2 a0 = (p[j] & 1) ? e2_1 : e2_0;
            const int2 a1 = (p[j] & 1) ? e2_3 : e2_2;
            const int2 e  = (p[j] & 2) ? a1 : a0;
            p[j] = 2 * p[j] + (xw[j][e.x] >= __int_as_float(e.y) ? 1 : 0);
        }
        // level 3 (LDS, transposed: p in [0,8))
        #pragma unroll
        for (int j = 0; j < 4; ++j) {
            const int2 e = tbl[(g << 8) + (p[j] << 5) + lt];
            p[j] = 2 * p[j] + (xw[j][e.x] >= __int_as_float(e.y) ? 1 : 0);
        }
        // level 4 (LDS, transposed: p in [0,16))
        #pragma unroll
        for (int j = 0; j < 4; ++j) {
            const int2 e = tbl[2048 + (g << 9) + (p[j] << 5) + lt];
            p[j] = 2 * p[j] + (xw[j][e.x] >= __int_as_float(e.y) ? 1 : 0);
        }
        // level 5 (global, L2-hot 32+32 KB tables; p in [0,32))
        #pragma unroll
        for (int j = 0; j < 4; ++j) {
            const int i5 = (t << 5) + p[j];
            const int   nf = n5[i5];
            const float bb = b5[i5];
            p[j] = 2 * p[j] + (xw[j][nf] >= bb ? 1 : 0);
        }

        // leaves (global, L2-hot) + coalesced out_val stores
        float4 leaf[4];
        #pragma unroll
        for (int j = 0; j < 4; ++j)
            leaf[j] = lf4[(size_t)t * 64 + p[j]];
        #pragma unroll
        for (int j = 0; j < 4; ++j)
            ov4[(size_t)(r0 + h + 2 * j) * NT + t] = leaf[j];

        // ---- per-group argmax (multiclass butterfly over 32 trees) ----
        #pragma unroll
        for (int j = 0; j < 4; ++j) {
            const float vc0 = leaf[j].x, vc1 = leaf[j].y,
                        vc2 = leaf[j].z, vc3 = leaf[j].w;
            // step 1 (mask 16): 4 shfl, keep 2 values per lane
            const float a0 = fmaxf(vc0, __shfl_xor(vc0, 16));
            const float a1 = fmaxf(vc1, __shfl_xor(vc1, 16));
            const float a2 = fmaxf(vc2, __shfl_xor(vc2, 16));
            const float a3 = fmaxf(vc3, __shfl_xor(vc3, 16));
            const bool hi4 = (lt & 16) != 0;
            float u = hi4 ? a2 : a0;
            float w = hi4 ? a3 : a1;
            // step 2 (mask 8): 2 shfl
            const float mu = fmaxf(u, __shfl_xor(u, 8));
            const float mw = fmaxf(w, __shfl_xor(w, 8));
            float v = (lt & 8) ? mw : mu;
            // steps 3-5 (masks 4,2,1)
            v = fmaxf(v, __shfl_xor(v, 4));
            v = fmaxf(v, __shfl_xor(v, 2));
            v = fmaxf(v, __shfl_xor(v, 1));
            // lane lt holds global max of class (2*(lt>>4&1) + (lt>>3&1))

            const float vcarr[4] = { vc0, vc1, vc2, vc3 };
            unsigned long long kk = 0;
            #pragma unroll
            for (int cls = 0; cls < 4; ++cls) {
                const float mc = __shfl(v, halfshift + (cls << 3));
                const unsigned long long ball = __ballot(vcarr[cls] == mc);
                const unsigned int hm = (unsigned int)(ball >> halfshift);
                const int gidx = g * TG + (__ffs(hm) - 1);   // first occurrence
                const unsigned long long kc =
                    ((unsigned long long)mono32(mc) << 8) |
                    (unsigned long long)(255 - gidx);
                if (lt == cls) kk = kc;
            }
            if (lt < 4) wkey[h + 2 * j][lt][g] = kk;
        }

        __syncthreads();   // wkey ready; prefetch (vmcnt) drained -> next buf valid

        // ---- cross-group combine: 32 threads finalize 8 rows x 4 classes ----
        if (tid < 32) {
            const int r = tid >> 2, c = tid & 3;
            unsigned long long m = wkey[r][c][0];
            #pragma unroll
            for (int q = 1; q < 8; ++q) {
                const unsigned long long v2 = wkey[r][c][q];
                m = (v2 > m) ? v2 : m;
            }
            out_arg[(size_t)(r0 + r) * NC + c] = (float)(255 - (int)(m & 0xFFull));
        }

        __syncthreads();   // wkey consumed before next chunk overwrites it
        buf ^= 1;
    }
}

extern "C" void kernel_launch(void* const* d_in, const int* in_sizes, int n_in,
                              void* d_out, int out_size, void* d_ws, size_t ws_size,
                              hipStream_t stream) {
    const float* x           = (const float*)d_in[0];
    const int*   root_nodes  = (const int*)  d_in[1];
    const float* root_biases = (const float*)d_in[2];
    const float* leaf_nodes  = (const float*)d_in[3];
    const int*   n1 = (const int*)  d_in[4];
    const float* b1 = (const float*)d_in[5];
    const int*   n2 = (const int*)  d_in[6];
    const float* b2 = (const float*)d_in[7];
    const int*   n3 = (const int*)  d_in[8];
    const float* b3 = (const float*)d_in[9];
    const int*   n4 = (const int*)  d_in[10];
    const float* b4 = (const float*)d_in[11];
    const int*   n5 = (const int*)  d_in[12];
    const float* b5 = (const float*)d_in[13];

    float* out_arg = (float*)d_out;                    // [B, C]
    float* out_val = (float*)d_out + (size_t)NB * NC;  // [B, T, C]

    k_traverse<<<RB, NTHREADS, 0, stream>>>(
        x, root_nodes, root_biases, leaf_nodes,
        n1, b1, n2, b2, n3, b3, n4, b4, n5, b5,
        out_val, out_arg);
}

// Round 3
// 405.055 us; speedup vs baseline: 1.0299x; 1.0171x over previous
//
#include <hip/hip_runtime.h>

// B=65536 rows, F=256 features, T=256 trees, DEPTH=6, C=4 classes.
#define NB 65536
#define NF 256
#define NT 256
#define NC 4
#define NG 8             // tree groups (32 trees each), one per wave
#define TG 32
#define RB 512           // row-blocks = grid size
#define RPB (NB / RB)    // 128 rows per block
#define RPC 8            // rows per chunk
#define NCHUNK (RPB / RPC)  // 16
#define NTHREADS 512     // 8 waves, wave w = tree group w

// Order-preserving float32 -> uint32 (inputs have no NaNs).
__device__ __forceinline__ unsigned int mono32(float v) {
    unsigned int u = __float_as_uint(v);
    return (u & 0x80000000u) ? ~u : (u | 0x80000000u);
}

// Circulant max-reduce over each 16-lane DPP row via v_max_f32 + row_ror
// {1,2,4,8}: after the 4 steps EVERY lane holds the max of its 16-row.
// Runs on the VALU pipe, not the LDS pipe (ds_swizzle/bpermute), which is
// the saturated resource in this kernel.
__device__ __forceinline__ float rowmax16_dpp(float v) {
    int i = __float_as_int(v);
    int r;
    r = __builtin_amdgcn_update_dpp(i, i, 0x121, 0xf, 0xf, true);  // row_ror:1
    i = __float_as_int(fmaxf(__int_as_float(i), __int_as_float(r)));
    r = __builtin_amdgcn_update_dpp(i, i, 0x122, 0xf, 0xf, true);  // row_ror:2
    i = __float_as_int(fmaxf(__int_as_float(i), __int_as_float(r)));
    r = __builtin_amdgcn_update_dpp(i, i, 0x124, 0xf, 0xf, true);  // row_ror:4
    i = __float_as_int(fmaxf(__int_as_float(i), __int_as_float(r)));
    r = __builtin_amdgcn_update_dpp(i, i, 0x128, 0xf, 0xf, true);  // row_ror:8
    i = __float_as_int(fmaxf(__int_as_float(i), __int_as_float(r)));
    return __int_as_float(i);
}

// Block = row-range of 128 rows x ALL 256 trees (8 waves = 8 tree groups).
// x staged once per row via global_load_lds (double-buffered prefetch).
// Levels 0..2 in registers; levels 3,4 in LDS transposed [p][tree]
// (2-way banks); level 5 + leaves gathered from L2-hot global.
// Argmax per group: DPP circulant rowmax (VALU) + one shfl_xor(16)/class,
// leaving the group max in ALL lanes -> ballot/ffs first-occurrence with
// no broadcast shuffles. Cross-group combine in LDS with double-buffered
// wkey so there is only ONE barrier (one vmcnt drain) per chunk.
__global__ __launch_bounds__(NTHREADS, 4) void k_traverse(
    const float* __restrict__ x,
    const int*   __restrict__ root_nodes, const float* __restrict__ root_biases,
    const float* __restrict__ leaf_nodes,
    const int* __restrict__ n1, const float* __restrict__ b1,
    const int* __restrict__ n2, const float* __restrict__ b2,
    const int* __restrict__ n3, const float* __restrict__ b3,
    const int* __restrict__ n4, const float* __restrict__ b4,
    const int* __restrict__ n5, const float* __restrict__ b5,
    float* __restrict__ out_val,   // [B, T, C]
    float* __restrict__ out_arg)   // [B, C]
{
    const int rb = blockIdx.x;

    __shared__ int2  tbl[6144];           // l3 [0,2048): g*256+p*32+lt ; l4 [2048,6144): g*512+p*32+lt
    __shared__ float xr[2][RPC * NF];     // double-buffered 8-row stage (2 x 8 KB)
    __shared__ unsigned long long wkey[2][RPC][NC][NG];  // dbuf argmax keys (4 KB)

    const int tid  = threadIdx.x;
    const int g    = tid >> 6;        // wave = tree group 0..7
    const int lane = tid & 63;
    const int lt   = lane & 31;       // local tree
    const int h    = lane >> 5;       // half: row parity
    const int t    = g * TG + lt;     // global tree
    const int halfshift = lane & 32;  // ballot half select

    // ---- per-thread register tables: root + levels 1,2 ----
    const int2 e0   = make_int2(root_nodes[t], __float_as_int(root_biases[t]));
    const int2 e1_0 = make_int2(n1[2 * t],     __float_as_int(b1[2 * t]));
    const int2 e1_1 = make_int2(n1[2 * t + 1], __float_as_int(b1[2 * t + 1]));
    const int2 e2_0 = make_int2(n2[4 * t],     __float_as_int(b2[4 * t]));
    const int2 e2_1 = make_int2(n2[4 * t + 1], __float_as_int(b2[4 * t + 1]));
    const int2 e2_2 = make_int2(n2[4 * t + 2], __float_as_int(b2[4 * t + 2]));
    const int2 e2_3 = make_int2(n2[4 * t + 3], __float_as_int(b2[4 * t + 3]));

    // ---- stage levels 3,4 for ALL groups into LDS, transposed [p][tree] ----
    #pragma unroll
    for (int k = 0; k < 4; ++k) {                      // level 3: 2048 entries (t*8+p)
        const int i = tid + 512 * k;
        const int tt = i >> 3, p = i & 7;
        tbl[((tt >> 5) << 8) + (p << 5) + (tt & 31)] =
            make_int2(n3[i], __float_as_int(b3[i]));
    }
    #pragma unroll
    for (int k = 0; k < 8; ++k) {                      // level 4: 4096 entries (t*16+p)
        const int i = tid + 512 * k;
        const int tt = i >> 4, p = i & 15;
        tbl[2048 + ((tt >> 5) << 9) + (p << 5) + (tt & 31)] =
            make_int2(n4[i], __float_as_int(b4[i]));
    }

    const float4* xg  = (const float4*)x;
    const float4* lf4 = (const float4*)leaf_nodes;
    float4*       ov4 = (float4*)out_val;

    // ---- prologue: stage chunk 0 into buffer 0 ----
    {
        const size_t base4 = (size_t)rb * RPB * (NF / 4);
        __builtin_amdgcn_global_load_lds(
            (const __attribute__((address_space(1))) void*)(xg + base4 + tid),
            (__attribute__((address_space(3))) void*)(((float4*)xr[0]) + tid),
            16, 0, 0);
    }
    __syncthreads();   // tables + chunk-0 stage complete

    int buf = 0;
    for (int ck = 0; ck < NCHUNK; ++ck) {
        const int r0 = rb * RPB + ck * RPC;
        const int kb = ck & 1;        // wkey buffer for this chunk

        // prefetch chunk ck+1 into the other buffer (drained by barrier below)
        if (ck + 1 < NCHUNK) {
            const size_t base4 = (size_t)(r0 + RPC) * (NF / 4);
            __builtin_amdgcn_global_load_lds(
                (const __attribute__((address_space(1))) void*)(xg + base4 + tid),
                (__attribute__((address_space(3))) void*)(((float4*)xr[buf ^ 1]) + tid),
                16, 0, 0);
        }

        // ---- 4 independent chains: rows h, h+2, h+4, h+6 ----
        const float* xb = xr[buf];
        const float* xw[4];
        int p[4];
        #pragma unroll
        for (int j = 0; j < 4; ++j) xw[j] = xb + (h + 2 * j) * NF;

        // root (regs)
        #pragma unroll
        for (int j = 0; j < 4; ++j)
            p[j] = (xw[j][e0.x] >= __int_as_float(e0.y)) ? 1 : 0;
        // level 1 (regs)
        #pragma unroll
        for (int j = 0; j < 4; ++j) {
            const int2 e = p[j] ? e1_1 : e1_0;
            p[j] = 2 * p[j] + (xw[j][e.x] >= __int_as_float(e.y) ? 1 : 0);
        }
        // level 2 (regs, 4-way select)
        #pragma unroll
        for (int j = 0; j < 4; ++j) {
            const int2 a0 = (p[j] & 1) ? e2_1 : e2_0;
            const int2 a1 = (p[j] & 1) ? e2_3 : e2_2;
            const int2 e  = (p[j] & 2) ? a1 : a0;
            p[j] = 2 * p[j] + (xw[j][e.x] >= __int_as_float(e.y) ? 1 : 0);
        }
        // level 3 (LDS, transposed: p in [0,8))
        #pragma unroll
        for (int j = 0; j < 4; ++j) {
            const int2 e = tbl[(g << 8) + (p[j] << 5) + lt];
            p[j] = 2 * p[j] + (xw[j][e.x] >= __int_as_float(e.y) ? 1 : 0);
        }
        // level 4 (LDS, transposed: p in [0,16))
        #pragma unroll
        for (int j = 0; j < 4; ++j) {
            const int2 e = tbl[2048 + (g << 9) + (p[j] << 5) + lt];
            p[j] = 2 * p[j] + (xw[j][e.x] >= __int_as_float(e.y) ? 1 : 0);
        }
        // level 5 (global, L2-hot 32+32 KB tables; p in [0,32))
        #pragma unroll
        for (int j = 0; j < 4; ++j) {
            const int i5 = (t << 5) + p[j];
            const int   nf = n5[i5];
            const float bb = b5[i5];
            p[j] = 2 * p[j] + (xw[j][nf] >= bb ? 1 : 0);
        }

        // leaves (global, L2-hot) + coalesced out_val stores
        float4 leaf[4];
        #pragma unroll
        for (int j = 0; j < 4; ++j)
            leaf[j] = lf4[(size_t)t * 64 + p[j]];
        #pragma unroll
        for (int j = 0; j < 4; ++j)
            ov4[(size_t)(r0 + h + 2 * j) * NT + t] = leaf[j];

        // ---- per-group argmax: DPP rowmax + one xor-16 per class ----
        #pragma unroll
        for (int j = 0; j < 4; ++j) {
            const float vcarr[4] = { leaf[j].x, leaf[j].y, leaf[j].z, leaf[j].w };
            unsigned long long kk = 0;
            #pragma unroll
            for (int cls = 0; cls < 4; ++cls) {
                float m = rowmax16_dpp(vcarr[cls]);          // VALU only
                m = fmaxf(m, __shfl_xor(m, 16));             // 1 LDS op
                // every lane of the 32-half now holds the group max
                const unsigned long long ball = __ballot(vcarr[cls] == m);
                const unsigned int hm = (unsigned int)(ball >> halfshift);
                const int gidx = g * TG + (__ffs(hm) - 1);   // first occurrence
                const unsigned long long kc =
                    ((unsigned long long)mono32(m) << 8) |
                    (unsigned long long)(255 - gidx);
                if (lt == cls) kk = kc;
            }
            if (lt < 4) wkey[kb][h + 2 * j][lt][g] = kk;
        }

        __syncthreads();   // wkey[kb] ready; prefetch drained -> next buf valid

        // ---- cross-group combine: 32 threads finalize 8 rows x 4 classes ----
        // runs concurrently with the next chunk's compute (wkey is dbuf'd)
        if (tid < 32) {
            const int r = tid >> 2, c = tid & 3;
            unsigned long long m = wkey[kb][r][c][0];
            #pragma unroll
            for (int q = 1; q < 8; ++q) {
                const unsigned long long v2 = wkey[kb][r][c][q];
                m = (v2 > m) ? v2 : m;
            }
            out_arg[(size_t)(r0 + r) * NC + c] = (float)(255 - (int)(m & 0xFFull));
        }

        buf ^= 1;
    }
}

extern "C" void kernel_launch(void* const* d_in, const int* in_sizes, int n_in,
                              void* d_out, int out_size, void* d_ws, size_t ws_size,
                              hipStream_t stream) {
    const float* x           = (const float*)d_in[0];
    const int*   root_nodes  = (const int*)  d_in[1];
    const float* root_biases = (const float*)d_in[2];
    const float* leaf_nodes  = (const float*)d_in[3];
    const int*   n1 = (const int*)  d_in[4];
    const float* b1 = (const float*)d_in[5];
    const int*   n2 = (const int*)  d_in[6];
    const float* b2 = (const float*)d_in[7];
    const int*   n3 = (const int*)  d_in[8];
    const float* b3 = (const float*)d_in[9];
    const int*   n4 = (const int*)  d_in[10];
    const float* b4 = (const float*)d_in[11];
    const int*   n5 = (const int*)  d_in[12];
    const float* b5 = (const float*)d_in[13];

    float* out_arg = (float*)d_out;                    // [B, C]
    float* out_val = (float*)d_out + (size_t)NB * NC;  // [B, T, C]

    k_traverse<<<RB, NTHREADS, 0, stream>>>(
        x, root_nodes, root_biases, leaf_nodes,
        n1, b1, n2, b2, n3, b3, n4, b4, n5, b5,
        out_val, out_arg);
}